// Round 10
// baseline (194.986 us; speedup 1.0000x reference)
//
#include <hip/hip_runtime.h>
#include <hip/hip_bf16.h>
#include <hip/hip_fp16.h>
#include <math.h>

#define N_NODES 8192
#define F_IN    512
#define C_OUT   128
#define CSR_CAP 128
#define NEG_SLOPE 0.2f

typedef float f4v __attribute__((ext_vector_type(4)));

__device__ __forceinline__ int lane_lt_popc(unsigned long long m) {
  return __builtin_amdgcn_mbcnt_hi((unsigned)(m >> 32),
         __builtin_amdgcn_mbcnt_lo((unsigned)m, 0u));
}

// ---------------------------------------------------------------------------
// K1: standalone gemm  [byte-identical to round 9; launched 3x as probe]
// ---------------------------------------------------------------------------
__global__ void __launch_bounds__(512) gemm_ft_kernel(
    const float* __restrict__ X, const float* __restrict__ W,
    const float* __restrict__ att_src, const float* __restrict__ att_dst,
    __half* __restrict__ ft16, float* __restrict__ asrc,
    float* __restrict__ adst, float* __restrict__ Spart)
{
  __shared__ float sx[32][36];
  __shared__ float sk[32][132];

  const int tid  = threadIdx.x;
  const int row0 = blockIdx.x * 32;
  const int rg   = tid >> 6;
  const int r0   = rg * 4;
  const int lane = tid & 63;
  const int c0   = lane * 2;

  float acc[4][2] = {};

  for (int kt = 0; kt < F_IN; kt += 32) {
    if (tid < 256) {
      int row = tid >> 3, kv = (tid & 7) * 4;
      f4v v = *(const f4v*)(X + (size_t)(row0 + row) * F_IN + kt + kv);
      *(f4v*)&sx[row][kv] = v;
    }
    #pragma unroll
    for (int q = 0; q < 2; ++q) {
      int idx = q * 512 + tid;
      int kk  = idx >> 5;
      int cc  = (idx & 31) * 4;
      *(f4v*)&sk[kk][cc] = *(const f4v*)(W + (size_t)(kt + kk) * C_OUT + cc);
    }
    __syncthreads();
    #pragma unroll
    for (int k = 0; k < 32; k += 4) {
      f4v a[4];
      float2 b[4];
      #pragma unroll
      for (int q = 0; q < 4; ++q) a[q] = *(const f4v*)&sx[r0 + q][k];
      #pragma unroll
      for (int q = 0; q < 4; ++q) b[q] = *(const float2*)&sk[k + q][c0];
      #pragma unroll
      for (int i = 0; i < 4; ++i) {
        acc[i][0] += a[i][0] * b[0].x; acc[i][1] += a[i][0] * b[0].y;
        acc[i][0] += a[i][1] * b[1].x; acc[i][1] += a[i][1] * b[1].y;
        acc[i][0] += a[i][2] * b[2].x; acc[i][1] += a[i][2] * b[2].y;
        acc[i][0] += a[i][3] * b[3].x; acc[i][1] += a[i][3] * b[3].y;
      }
    }
    __syncthreads();
  }

  #pragma unroll
  for (int i = 0; i < 4; ++i) {
    __half2 h = __floats2half2_rn(acc[i][0], acc[i][1]);
    ((__half2*)ft16)[(size_t)(row0 + r0 + i) * 64 + lane] = h;
  }

  float2 as = *(const float2*)(att_src + c0);
  float2 ad = *(const float2*)(att_dst + c0);
  #pragma unroll
  for (int i = 0; i < 4; ++i) {
    float ps = acc[i][0] * as.x + acc[i][1] * as.y;
    float pd = acc[i][0] * ad.x + acc[i][1] * ad.y;
    #pragma unroll
    for (int off = 32; off > 0; off >>= 1) {
      ps += __shfl_xor(ps, off);
      pd += __shfl_xor(pd, off);
    }
    if (lane == 0) {
      asrc[row0 + r0 + i] = ps;
      adst[row0 + r0 + i] = pd;
    }
  }

  float* scp = &sx[0][0];
  float s0 = acc[0][0] + acc[1][0] + acc[2][0] + acc[3][0];
  float s1 = acc[0][1] + acc[1][1] + acc[2][1] + acc[3][1];
  *(float2*)&scp[rg * 128 + c0] = make_float2(s0, s1);
  __syncthreads();
  if (tid < 128) {
    float s = 0.f;
    #pragma unroll
    for (int q = 0; q < 8; ++q) s += scp[q * 128 + tid];
    Spart[(size_t)blockIdx.x * 128 + tid] = s;
  }
}

// ---------------------------------------------------------------------------
// K2: colsum  [byte-identical to round 9]
// ---------------------------------------------------------------------------
__global__ void __launch_bounds__(256) colsum_par_kernel(
    const float* __restrict__ Spart, float* __restrict__ S)
{
  __shared__ float wpart[4];
  const int c = blockIdx.x;
  const int t = threadIdx.x;
  const int lane = t & 63, w = t >> 6;
  float v = Spart[(size_t)t * 128 + c];
  #pragma unroll
  for (int off = 32; off > 0; off >>= 1) v += __shfl_xor(v, off);
  if (lane == 0) wpart[w] = v;
  __syncthreads();
  if (t == 0) S[c] = wpart[0] + wpart[1] + wpart[2] + wpart[3];
}

// ---------------------------------------------------------------------------
// K3: fused scan+gather  [byte-identical to round 9; launched 2x as probe]
// ---------------------------------------------------------------------------
__global__ void __launch_bounds__(512) scan_gather_all_kernel(
    const float* __restrict__ adj, const __half* __restrict__ ft16,
    const float* __restrict__ asrc, const float* __restrict__ adst,
    const float* __restrict__ S, float* __restrict__ out)
{
  __shared__ int   sj[8][CSR_CAP];
  __shared__ float sw[8][CSR_CAP];

  const int lane = threadIdx.x & 63;
  const int wv   = threadIdx.x >> 6;
  const int row  = blockIdx.x * 8 + wv;
  const f4v* rp  = (const f4v*)(adj + (size_t)row * N_NODES);

  int base = 0;
  for (int cb = 0; cb < 32; cb += 8) {
    f4v v[8];
    #pragma unroll
    for (int q = 0; q < 8; ++q)
      v[q] = __builtin_nontemporal_load(&rp[(cb + q) * 64 + lane]);
    #pragma unroll
    for (int q = 0; q < 8; ++q) {
      const int colb = (cb + q) * 256 + lane * 4;
      unsigned long long b0 = __ballot(v[q][0] != 0.f);
      unsigned long long b1 = __ballot(v[q][1] != 0.f);
      unsigned long long b2 = __ballot(v[q][2] != 0.f);
      unsigned long long b3 = __ballot(v[q][3] != 0.f);
      int o = base + lane_lt_popc(b0) + lane_lt_popc(b1)
                   + lane_lt_popc(b2) + lane_lt_popc(b3);
      if ((b0 >> lane) & 1ull) { if (o < CSR_CAP) sj[wv][o] = colb + 0; ++o; }
      if ((b1 >> lane) & 1ull) { if (o < CSR_CAP) sj[wv][o] = colb + 1; ++o; }
      if ((b2 >> lane) & 1ull) { if (o < CSR_CAP) sj[wv][o] = colb + 2; ++o; }
      if ((b3 >> lane) & 1ull) { if (o < CSR_CAP) sj[wv][o] = colb + 3; ++o; }
      base += __popcll(b0) + __popcll(b1) + __popcll(b2) + __popcll(b3);
    }
  }
  const int cnt = base < CSR_CAP ? base : CSR_CAP;

  const float ai = asrc[row];
  float dsum = 0.f;
  for (int e = lane; e < cnt; e += 64) {
    int j = sj[wv][e];
    float s = ai + adst[j];
    float l = s < 0.f ? NEG_SLOPE * s : s;
    float w = expf(l);
    sw[wv][e] = w - 1.0f;
    dsum += w;
  }
  #pragma unroll
  for (int off = 32; off > 0; off >>= 1) dsum += __shfl_xor(dsum, off);
  const float denom = (float)(N_NODES - cnt) + dsum;

  float2 acc = make_float2(0.f, 0.f);
  const __half2* f2 = (const __half2*)ft16;
  int e = 0;
  for (; e + 4 <= cnt; e += 4) {
    int   j0 = sj[wv][e+0], j1 = sj[wv][e+1], j2 = sj[wv][e+2], j3 = sj[wv][e+3];
    float w0 = sw[wv][e+0], w1 = sw[wv][e+1], w2 = sw[wv][e+2], w3 = sw[wv][e+3];
    float2 f0 = __half22float2(f2[(size_t)j0 * 64 + lane]);
    float2 f1 = __half22float2(f2[(size_t)j1 * 64 + lane]);
    float2 g2 = __half22float2(f2[(size_t)j2 * 64 + lane]);
    float2 f3 = __half22float2(f2[(size_t)j3 * 64 + lane]);
    acc.x += w0 * f0.x; acc.y += w0 * f0.y;
    acc.x += w1 * f1.x; acc.y += w1 * f1.y;
    acc.x += w2 * g2.x; acc.y += w2 * g2.y;
    acc.x += w3 * f3.x; acc.y += w3 * f3.y;
  }
  for (; e < cnt; ++e) {
    int   j = sj[wv][e];
    float w = sw[wv][e];
    float2 f = __half22float2(f2[(size_t)j * 64 + lane]);
    acc.x += w * f.x; acc.y += w * f.y;
  }

  float2 sv = ((const float2*)S)[lane];
  float ox = (sv.x + acc.x) / denom;
  float oy = (sv.y + acc.y) / denom;
  ox = ox > 0.f ? ox : expm1f(ox);
  oy = oy > 0.f ? oy : expm1f(oy);
  ((float2*)out)[(size_t)row * 64 + lane] = make_float2(ox, oy);
}

// ---------------------------------------------------------------------------
// DUAL ATTRIBUTION PROBE (all kernels idempotent):
//   gemm x3, scan_gather x2  ->  dur10 = 3G + 2F + c ;  dur9 = G + F + c
//   G = dur10 - 2*dur9 + c ;  F = dur9 - c - G   (c = colsum+gaps ~ 3 us)
// ---------------------------------------------------------------------------
extern "C" void kernel_launch(void* const* d_in, const int* in_sizes, int n_in,
                              void* d_out, int out_size, void* d_ws, size_t ws_size,
                              hipStream_t stream)
{
  const float* X       = (const float*)d_in[0];   // features 8192x512
  const float* adj     = (const float*)d_in[1];   // adjacency 8192x8192
  const float* W       = (const float*)d_in[2];   // kernel 512x128
  const float* att_src = (const float*)d_in[3];   // 128
  const float* att_dst = (const float*)d_in[4];   // 128
  float* out = (float*)d_out;

  float* ws    = (float*)d_ws;
  float* asrc  = ws;                                    // 8192
  float* adst  = asrc + N_NODES;                        // 8192
  float* Spart = adst + N_NODES;                        // 256*128
  float* S     = Spart + 256 * 128;                     // 128
  __half* ft16 = (__half*)(S + 128);                    // 8192*128 fp16

  gemm_ft_kernel<<<256, 512, 0, stream>>>(X, W, att_src, att_dst,
                                          ft16, asrc, adst, Spart);
  gemm_ft_kernel<<<256, 512, 0, stream>>>(X, W, att_src, att_dst,
                                          ft16, asrc, adst, Spart);
  gemm_ft_kernel<<<256, 512, 0, stream>>>(X, W, att_src, att_dst,
                                          ft16, asrc, adst, Spart);
  colsum_par_kernel<<<128, 256, 0, stream>>>(Spart, S);
  scan_gather_all_kernel<<<N_NODES / 8, 512, 0, stream>>>(adj, ft16, asrc,
                                                          adst, S, out);
  scan_gather_all_kernel<<<N_NODES / 8, 512, 0, stream>>>(adj, ft16, asrc,
                                                          adst, S, out);
}

// Round 11
// 71.420 us; speedup vs baseline: 2.7301x; 2.7301x over previous
//
#include <hip/hip_runtime.h>
#include <hip/hip_bf16.h>
#include <hip/hip_fp16.h>
#include <math.h>

#define N_NODES 8192
#define F_IN    512
#define C_OUT   128
#define CSR_CAP 128
#define NEG_SLOPE 0.2f

typedef float f4v __attribute__((ext_vector_type(4)));

__device__ __forceinline__ int lane_lt_popc(unsigned long long m) {
  return __builtin_amdgcn_mbcnt_hi((unsigned)(m >> 32),
         __builtin_amdgcn_mbcnt_lo((unsigned)m, 0u));
}

// ---------------------------------------------------------------------------
// K1: 512 blocks x 512 thr  ==  2 blocks/CU exactly (co-resident from t=0).
//   bid < 256  -> gemm role: ft16 = half(X@W), asrc/adst dots, Spart.
//   bid >= 256 -> scan role: each wave scans 4 consecutive rows -> HBM CSR.
// The 20 us gemm hides under the 44.6 us adjacency stream.
// ---------------------------------------------------------------------------
__global__ void __launch_bounds__(512) fat_kernel(
    const float* __restrict__ adj, int* __restrict__ counts,
    unsigned short* __restrict__ elist,
    const float* __restrict__ X, const float* __restrict__ W,
    const float* __restrict__ att_src, const float* __restrict__ att_dst,
    __half* __restrict__ ft16, float* __restrict__ asrc,
    float* __restrict__ adst, float* __restrict__ Spart)
{
  __shared__ float sx[32][36];
  __shared__ float sk[32][132];

  const int bid = blockIdx.x;
  const int tid = threadIdx.x;

  if (bid < 256) {
    // ---------------- gemm role ----------------
    const int row0 = bid * 32;
    const int rg   = tid >> 6;
    const int r0   = rg * 4;
    const int lane = tid & 63;
    const int c0   = lane * 2;

    float acc[4][2] = {};

    for (int kt = 0; kt < F_IN; kt += 32) {
      if (tid < 256) {
        int row = tid >> 3, kv = (tid & 7) * 4;
        f4v v = *(const f4v*)(X + (size_t)(row0 + row) * F_IN + kt + kv);
        *(f4v*)&sx[row][kv] = v;
      }
      #pragma unroll
      for (int q = 0; q < 2; ++q) {
        int idx = q * 512 + tid;
        int kk  = idx >> 5;
        int cc  = (idx & 31) * 4;
        *(f4v*)&sk[kk][cc] = *(const f4v*)(W + (size_t)(kt + kk) * C_OUT + cc);
      }
      __syncthreads();
      #pragma unroll
      for (int k = 0; k < 32; k += 4) {
        f4v a[4];
        float2 b[4];
        #pragma unroll
        for (int q = 0; q < 4; ++q) a[q] = *(const f4v*)&sx[r0 + q][k];
        #pragma unroll
        for (int q = 0; q < 4; ++q) b[q] = *(const float2*)&sk[k + q][c0];
        #pragma unroll
        for (int i = 0; i < 4; ++i) {
          acc[i][0] += a[i][0] * b[0].x; acc[i][1] += a[i][0] * b[0].y;
          acc[i][0] += a[i][1] * b[1].x; acc[i][1] += a[i][1] * b[1].y;
          acc[i][0] += a[i][2] * b[2].x; acc[i][1] += a[i][2] * b[2].y;
          acc[i][0] += a[i][3] * b[3].x; acc[i][1] += a[i][3] * b[3].y;
        }
      }
      __syncthreads();
    }

    #pragma unroll
    for (int i = 0; i < 4; ++i) {
      __half2 h = __floats2half2_rn(acc[i][0], acc[i][1]);
      ((__half2*)ft16)[(size_t)(row0 + r0 + i) * 64 + lane] = h;
    }

    float2 as = *(const float2*)(att_src + c0);
    float2 ad = *(const float2*)(att_dst + c0);
    #pragma unroll
    for (int i = 0; i < 4; ++i) {
      float ps = acc[i][0] * as.x + acc[i][1] * as.y;
      float pd = acc[i][0] * ad.x + acc[i][1] * ad.y;
      #pragma unroll
      for (int off = 32; off > 0; off >>= 1) {
        ps += __shfl_xor(ps, off);
        pd += __shfl_xor(pd, off);
      }
      if (lane == 0) {
        asrc[row0 + r0 + i] = ps;
        adst[row0 + r0 + i] = pd;
      }
    }

    float* scp = &sx[0][0];
    float s0 = acc[0][0] + acc[1][0] + acc[2][0] + acc[3][0];
    float s1 = acc[0][1] + acc[1][1] + acc[2][1] + acc[3][1];
    *(float2*)&scp[rg * 128 + c0] = make_float2(s0, s1);
    __syncthreads();
    if (tid < 128) {
      float s = 0.f;
      #pragma unroll
      for (int q = 0; q < 8; ++q) s += scp[q * 128 + tid];
      Spart[(size_t)bid * 128 + tid] = s;
    }
  } else {
    // ---------------- scan role: 4 rows per wave -> HBM CSR ----------------
    const int sb   = bid - 256;            // 0..255
    const int lane = tid & 63;
    const int wv   = tid >> 6;

    for (int t = 0; t < 4; ++t) {
      const int row = sb * 32 + wv * 4 + t;
      const f4v* rp = (const f4v*)(adj + (size_t)row * N_NODES);
      unsigned short* er = elist + (size_t)row * CSR_CAP;

      int base = 0;
      for (int cb = 0; cb < 32; cb += 8) {
        f4v v[8];
        #pragma unroll
        for (int q = 0; q < 8; ++q)
          v[q] = __builtin_nontemporal_load(&rp[(cb + q) * 64 + lane]);
        #pragma unroll
        for (int q = 0; q < 8; ++q) {
          const int colb = (cb + q) * 256 + lane * 4;
          unsigned long long b0 = __ballot(v[q][0] != 0.f);
          unsigned long long b1 = __ballot(v[q][1] != 0.f);
          unsigned long long b2 = __ballot(v[q][2] != 0.f);
          unsigned long long b3 = __ballot(v[q][3] != 0.f);
          int o = base + lane_lt_popc(b0) + lane_lt_popc(b1)
                       + lane_lt_popc(b2) + lane_lt_popc(b3);
          if ((b0 >> lane) & 1ull) { if (o < CSR_CAP) er[o] = (unsigned short)(colb + 0); ++o; }
          if ((b1 >> lane) & 1ull) { if (o < CSR_CAP) er[o] = (unsigned short)(colb + 1); ++o; }
          if ((b2 >> lane) & 1ull) { if (o < CSR_CAP) er[o] = (unsigned short)(colb + 2); ++o; }
          if ((b3 >> lane) & 1ull) { if (o < CSR_CAP) er[o] = (unsigned short)(colb + 3); ++o; }
          base += __popcll(b0) + __popcll(b1) + __popcll(b2) + __popcll(b3);
        }
      }
      if (lane == 0) counts[row] = base < CSR_CAP ? base : CSR_CAP;
    }
  }
}

// ---------------------------------------------------------------------------
// K2: colsum — block c sums Spart[0..255][c].
// ---------------------------------------------------------------------------
__global__ void __launch_bounds__(256) colsum_par_kernel(
    const float* __restrict__ Spart, float* __restrict__ S)
{
  __shared__ float wpart[4];
  const int c = blockIdx.x;
  const int t = threadIdx.x;
  const int lane = t & 63, w = t >> 6;
  float v = Spart[(size_t)t * 128 + c];
  #pragma unroll
  for (int off = 32; off > 0; off >>= 1) v += __shfl_xor(v, off);
  if (lane == 0) wpart[w] = v;
  __syncthreads();
  if (t == 0) S[c] = wpart[0] + wpart[1] + wpart[2] + wpart[3];
}

// ---------------------------------------------------------------------------
// K3: gather-only for ALL rows from HBM CSR. One wave per row; no adjacency
// stream running -> ft16 (2 MB) is L2-resident; gathers are coalesced 256 B.
// ---------------------------------------------------------------------------
__global__ void __launch_bounds__(512) gather_all_kernel(
    const int* __restrict__ counts, const unsigned short* __restrict__ elist,
    const __half* __restrict__ ft16, const float* __restrict__ asrc,
    const float* __restrict__ adst, const float* __restrict__ S,
    float* __restrict__ out)
{
  __shared__ int   sj[8][CSR_CAP];
  __shared__ float sw[8][CSR_CAP];

  const int lane = threadIdx.x & 63;
  const int wv   = threadIdx.x >> 6;
  const int row  = blockIdx.x * 8 + wv;
  const int cnt  = counts[row];
  const float ai = asrc[row];
  const unsigned short* er = elist + (size_t)row * CSR_CAP;

  float dsum = 0.f;
  for (int e = lane; e < cnt; e += 64) {
    int j = er[e];
    float s = ai + adst[j];
    float l = s < 0.f ? NEG_SLOPE * s : s;
    float w = expf(l);
    sj[wv][e] = j;
    sw[wv][e] = w - 1.0f;
    dsum += w;
  }
  #pragma unroll
  for (int off = 32; off > 0; off >>= 1) dsum += __shfl_xor(dsum, off);
  const float denom = (float)(N_NODES - cnt) + dsum;
  // same-wave LDS RAW (no barrier needed; pattern proven in R7/R8)

  float2 acc = make_float2(0.f, 0.f);
  const __half2* f2 = (const __half2*)ft16;
  int e = 0;
  for (; e + 4 <= cnt; e += 4) {
    int   j0 = sj[wv][e+0], j1 = sj[wv][e+1], j2 = sj[wv][e+2], j3 = sj[wv][e+3];
    float w0 = sw[wv][e+0], w1 = sw[wv][e+1], w2 = sw[wv][e+2], w3 = sw[wv][e+3];
    float2 f0 = __half22float2(f2[(size_t)j0 * 64 + lane]);
    float2 f1 = __half22float2(f2[(size_t)j1 * 64 + lane]);
    float2 g2 = __half22float2(f2[(size_t)j2 * 64 + lane]);
    float2 f3 = __half22float2(f2[(size_t)j3 * 64 + lane]);
    acc.x += w0 * f0.x; acc.y += w0 * f0.y;
    acc.x += w1 * f1.x; acc.y += w1 * f1.y;
    acc.x += w2 * g2.x; acc.y += w2 * g2.y;
    acc.x += w3 * f3.x; acc.y += w3 * f3.y;
  }
  for (; e < cnt; ++e) {
    int   j = sj[wv][e];
    float w = sw[wv][e];
    float2 f = __half22float2(f2[(size_t)j * 64 + lane]);
    acc.x += w * f.x; acc.y += w * f.y;
  }

  float2 sv = ((const float2*)S)[lane];
  float ox = (sv.x + acc.x) / denom;
  float oy = (sv.y + acc.y) / denom;
  ox = ox > 0.f ? ox : expm1f(ox);
  oy = oy > 0.f ? oy : expm1f(oy);
  ((float2*)out)[(size_t)row * 64 + lane] = make_float2(ox, oy);
}

// ---------------------------------------------------------------------------
extern "C" void kernel_launch(void* const* d_in, const int* in_sizes, int n_in,
                              void* d_out, int out_size, void* d_ws, size_t ws_size,
                              hipStream_t stream)
{
  const float* X       = (const float*)d_in[0];   // features 8192x512
  const float* adj     = (const float*)d_in[1];   // adjacency 8192x8192
  const float* W       = (const float*)d_in[2];   // kernel 512x128
  const float* att_src = (const float*)d_in[3];   // 128
  const float* att_dst = (const float*)d_in[4];   // 128
  float* out = (float*)d_out;

  float* ws    = (float*)d_ws;
  float* asrc  = ws;                                    // 8192
  float* adst  = asrc + N_NODES;                        // 8192
  float* Spart = adst + N_NODES;                        // 256*128
  float* S     = Spart + 256 * 128;                     // 128
  int*   counts = (int*)(S + 128);                      // 8192
  __half* ft16 = (__half*)(counts + N_NODES);           // 8192*128 fp16
  unsigned short* elist =
      (unsigned short*)(ft16 + (size_t)N_NODES * C_OUT); // 8192*128 u16

  fat_kernel<<<512, 512, 0, stream>>>(adj, counts, elist,
                                      X, W, att_src, att_dst,
                                      ft16, asrc, adst, Spart);
  colsum_par_kernel<<<128, 256, 0, stream>>>(Spart, S);
  gather_all_kernel<<<N_NODES / 8, 512, 0, stream>>>(counts, elist, ft16,
                                                     asrc, adst, S, out);
}

// Round 12
// 67.132 us; speedup vs baseline: 2.9045x; 1.0639x over previous
//
#include <hip/hip_runtime.h>
#include <hip/hip_bf16.h>
#include <hip/hip_fp16.h>
#include <math.h>

#define N_NODES 8192
#define F_IN    512
#define C_OUT   128
#define CSR_CAP 128
#define NEG_SLOPE 0.2f

typedef float f4v __attribute__((ext_vector_type(4)));

__device__ __forceinline__ int lane_lt_popc(unsigned long long m) {
  return __builtin_amdgcn_mbcnt_hi((unsigned)(m >> 32),
         __builtin_amdgcn_mbcnt_lo((unsigned)m, 0u));
}

// ---------------------------------------------------------------------------
// K1: 1280 blocks x 512 thr.
//   bid < 256  -> gemm role (dispatched first, co-resident with stream).
//   bid >= 256 -> scan role: ONE row per wave (R5's max-MLP shape, 8192
//                 stream waves total; 1024 blocks resident at 4/CU, last 256
//                 backfill -> HBM stays saturated).
// ---------------------------------------------------------------------------
__global__ void __launch_bounds__(512) fat_kernel(
    const float* __restrict__ adj, int* __restrict__ counts,
    unsigned short* __restrict__ elist,
    const float* __restrict__ X, const float* __restrict__ W,
    const float* __restrict__ att_src, const float* __restrict__ att_dst,
    __half* __restrict__ ft16, float* __restrict__ asrc,
    float* __restrict__ adst, float* __restrict__ Spart)
{
  __shared__ float sx[32][36];
  __shared__ float sk[32][132];

  const int bid = blockIdx.x;
  const int tid = threadIdx.x;

  if (bid < 256) {
    // ---------------- gemm role ----------------
    const int row0 = bid * 32;
    const int rg   = tid >> 6;
    const int r0   = rg * 4;
    const int lane = tid & 63;
    const int c0   = lane * 2;

    float acc[4][2] = {};

    for (int kt = 0; kt < F_IN; kt += 32) {
      if (tid < 256) {
        int row = tid >> 3, kv = (tid & 7) * 4;
        f4v v = *(const f4v*)(X + (size_t)(row0 + row) * F_IN + kt + kv);
        *(f4v*)&sx[row][kv] = v;
      }
      #pragma unroll
      for (int q = 0; q < 2; ++q) {
        int idx = q * 512 + tid;
        int kk  = idx >> 5;
        int cc  = (idx & 31) * 4;
        *(f4v*)&sk[kk][cc] = *(const f4v*)(W + (size_t)(kt + kk) * C_OUT + cc);
      }
      __syncthreads();
      #pragma unroll
      for (int k = 0; k < 32; k += 4) {
        f4v a[4];
        float2 b[4];
        #pragma unroll
        for (int q = 0; q < 4; ++q) a[q] = *(const f4v*)&sx[r0 + q][k];
        #pragma unroll
        for (int q = 0; q < 4; ++q) b[q] = *(const float2*)&sk[k + q][c0];
        #pragma unroll
        for (int i = 0; i < 4; ++i) {
          acc[i][0] += a[i][0] * b[0].x; acc[i][1] += a[i][0] * b[0].y;
          acc[i][0] += a[i][1] * b[1].x; acc[i][1] += a[i][1] * b[1].y;
          acc[i][0] += a[i][2] * b[2].x; acc[i][1] += a[i][2] * b[2].y;
          acc[i][0] += a[i][3] * b[3].x; acc[i][1] += a[i][3] * b[3].y;
        }
      }
      __syncthreads();
    }

    #pragma unroll
    for (int i = 0; i < 4; ++i) {
      __half2 h = __floats2half2_rn(acc[i][0], acc[i][1]);
      ((__half2*)ft16)[(size_t)(row0 + r0 + i) * 64 + lane] = h;
    }

    float2 as = *(const float2*)(att_src + c0);
    float2 ad = *(const float2*)(att_dst + c0);
    #pragma unroll
    for (int i = 0; i < 4; ++i) {
      float ps = acc[i][0] * as.x + acc[i][1] * as.y;
      float pd = acc[i][0] * ad.x + acc[i][1] * ad.y;
      #pragma unroll
      for (int off = 32; off > 0; off >>= 1) {
        ps += __shfl_xor(ps, off);
        pd += __shfl_xor(pd, off);
      }
      if (lane == 0) {
        asrc[row0 + r0 + i] = ps;
        adst[row0 + r0 + i] = pd;
      }
    }

    float* scp = &sx[0][0];
    float s0 = acc[0][0] + acc[1][0] + acc[2][0] + acc[3][0];
    float s1 = acc[0][1] + acc[1][1] + acc[2][1] + acc[3][1];
    *(float2*)&scp[rg * 128 + c0] = make_float2(s0, s1);
    __syncthreads();
    if (tid < 128) {
      float s = 0.f;
      #pragma unroll
      for (int q = 0; q < 8; ++q) s += scp[q * 128 + tid];
      Spart[(size_t)bid * 128 + tid] = s;
    }
  } else {
    // ---------------- scan role: ONE row per wave -> HBM CSR ----------------
    const int sb   = bid - 256;            // 0..1023
    const int lane = tid & 63;
    const int wv   = tid >> 6;
    const int row  = sb * 8 + wv;
    const f4v* rp  = (const f4v*)(adj + (size_t)row * N_NODES);
    unsigned short* er = elist + (size_t)row * CSR_CAP;

    int base = 0;
    for (int cb = 0; cb < 32; cb += 8) {
      f4v v[8];
      #pragma unroll
      for (int q = 0; q < 8; ++q)
        v[q] = __builtin_nontemporal_load(&rp[(cb + q) * 64 + lane]);
      #pragma unroll
      for (int q = 0; q < 8; ++q) {
        const int colb = (cb + q) * 256 + lane * 4;
        unsigned long long b0 = __ballot(v[q][0] != 0.f);
        unsigned long long b1 = __ballot(v[q][1] != 0.f);
        unsigned long long b2 = __ballot(v[q][2] != 0.f);
        unsigned long long b3 = __ballot(v[q][3] != 0.f);
        int o = base + lane_lt_popc(b0) + lane_lt_popc(b1)
                     + lane_lt_popc(b2) + lane_lt_popc(b3);
        if ((b0 >> lane) & 1ull) { if (o < CSR_CAP) er[o] = (unsigned short)(colb + 0); ++o; }
        if ((b1 >> lane) & 1ull) { if (o < CSR_CAP) er[o] = (unsigned short)(colb + 1); ++o; }
        if ((b2 >> lane) & 1ull) { if (o < CSR_CAP) er[o] = (unsigned short)(colb + 2); ++o; }
        if ((b3 >> lane) & 1ull) { if (o < CSR_CAP) er[o] = (unsigned short)(colb + 3); ++o; }
        base += __popcll(b0) + __popcll(b1) + __popcll(b2) + __popcll(b3);
      }
    }
    if (lane == 0) counts[row] = base < CSR_CAP ? base : CSR_CAP;
  }
}

// ---------------------------------------------------------------------------
// K2: colsum — block c sums Spart[0..255][c].
// ---------------------------------------------------------------------------
__global__ void __launch_bounds__(256) colsum_par_kernel(
    const float* __restrict__ Spart, float* __restrict__ S)
{
  __shared__ float wpart[4];
  const int c = blockIdx.x;
  const int t = threadIdx.x;
  const int lane = t & 63, w = t >> 6;
  float v = Spart[(size_t)t * 128 + c];
  #pragma unroll
  for (int off = 32; off > 0; off >>= 1) v += __shfl_xor(v, off);
  if (lane == 0) wpart[w] = v;
  __syncthreads();
  if (t == 0) S[c] = wpart[0] + wpart[1] + wpart[2] + wpart[3];
}

// ---------------------------------------------------------------------------
// K3: gather-only, one wave per row. Unroll-8 gather: ~4 vmcnt rounds per
// row instead of ~9 (latency-bound -> halve serialized rounds).
// ---------------------------------------------------------------------------
__global__ void __launch_bounds__(512) gather_all_kernel(
    const int* __restrict__ counts, const unsigned short* __restrict__ elist,
    const __half* __restrict__ ft16, const float* __restrict__ asrc,
    const float* __restrict__ adst, const float* __restrict__ S,
    float* __restrict__ out)
{
  __shared__ int   sj[8][CSR_CAP];
  __shared__ float sw[8][CSR_CAP];

  const int lane = threadIdx.x & 63;
  const int wv   = threadIdx.x >> 6;
  const int row  = blockIdx.x * 8 + wv;
  const int cnt  = counts[row];
  const float ai = asrc[row];
  const unsigned short* er = elist + (size_t)row * CSR_CAP;

  float dsum = 0.f;
  for (int e = lane; e < cnt; e += 64) {
    int j = er[e];
    float s = ai + adst[j];
    float l = s < 0.f ? NEG_SLOPE * s : s;
    float w = expf(l);
    sj[wv][e] = j;
    sw[wv][e] = w - 1.0f;
    dsum += w;
  }
  #pragma unroll
  for (int off = 32; off > 0; off >>= 1) dsum += __shfl_xor(dsum, off);
  const float denom = (float)(N_NODES - cnt) + dsum;
  // same-wave LDS RAW (no barrier; pattern proven R7/R8/R11)

  float2 acc = make_float2(0.f, 0.f);
  const __half2* f2 = (const __half2*)ft16;
  int e = 0;
  for (; e + 8 <= cnt; e += 8) {
    int   j0 = sj[wv][e+0], j1 = sj[wv][e+1], j2 = sj[wv][e+2], j3 = sj[wv][e+3];
    int   j4 = sj[wv][e+4], j5 = sj[wv][e+5], j6 = sj[wv][e+6], j7 = sj[wv][e+7];
    float2 f0 = __half22float2(f2[(size_t)j0 * 64 + lane]);
    float2 f1 = __half22float2(f2[(size_t)j1 * 64 + lane]);
    float2 g2 = __half22float2(f2[(size_t)j2 * 64 + lane]);
    float2 f3 = __half22float2(f2[(size_t)j3 * 64 + lane]);
    float2 f4 = __half22float2(f2[(size_t)j4 * 64 + lane]);
    float2 f5 = __half22float2(f2[(size_t)j5 * 64 + lane]);
    float2 f6 = __half22float2(f2[(size_t)j6 * 64 + lane]);
    float2 f7 = __half22float2(f2[(size_t)j7 * 64 + lane]);
    float w0 = sw[wv][e+0], w1 = sw[wv][e+1], w2 = sw[wv][e+2], w3 = sw[wv][e+3];
    float w4 = sw[wv][e+4], w5 = sw[wv][e+5], w6 = sw[wv][e+6], w7 = sw[wv][e+7];
    acc.x += w0 * f0.x; acc.y += w0 * f0.y;
    acc.x += w1 * f1.x; acc.y += w1 * f1.y;
    acc.x += w2 * g2.x; acc.y += w2 * g2.y;
    acc.x += w3 * f3.x; acc.y += w3 * f3.y;
    acc.x += w4 * f4.x; acc.y += w4 * f4.y;
    acc.x += w5 * f5.x; acc.y += w5 * f5.y;
    acc.x += w6 * f6.x; acc.y += w6 * f6.y;
    acc.x += w7 * f7.x; acc.y += w7 * f7.y;
  }
  for (; e < cnt; ++e) {
    int   j = sj[wv][e];
    float w = sw[wv][e];
    float2 f = __half22float2(f2[(size_t)j * 64 + lane]);
    acc.x += w * f.x; acc.y += w * f.y;
  }

  float2 sv = ((const float2*)S)[lane];
  float ox = (sv.x + acc.x) / denom;
  float oy = (sv.y + acc.y) / denom;
  ox = ox > 0.f ? ox : expm1f(ox);
  oy = oy > 0.f ? oy : expm1f(oy);
  ((float2*)out)[(size_t)row * 64 + lane] = make_float2(ox, oy);
}

// ---------------------------------------------------------------------------
extern "C" void kernel_launch(void* const* d_in, const int* in_sizes, int n_in,
                              void* d_out, int out_size, void* d_ws, size_t ws_size,
                              hipStream_t stream)
{
  const float* X       = (const float*)d_in[0];   // features 8192x512
  const float* adj     = (const float*)d_in[1];   // adjacency 8192x8192
  const float* W       = (const float*)d_in[2];   // kernel 512x128
  const float* att_src = (const float*)d_in[3];   // 128
  const float* att_dst = (const float*)d_in[4];   // 128
  float* out = (float*)d_out;

  float* ws    = (float*)d_ws;
  float* asrc  = ws;                                    // 8192
  float* adst  = asrc + N_NODES;                        // 8192
  float* Spart = adst + N_NODES;                        // 256*128
  float* S     = Spart + 256 * 128;                     // 128
  int*   counts = (int*)(S + 128);                      // 8192
  __half* ft16 = (__half*)(counts + N_NODES);           // 8192*128 fp16
  unsigned short* elist =
      (unsigned short*)(ft16 + (size_t)N_NODES * C_OUT); // 8192*128 u16

  fat_kernel<<<1280, 512, 0, stream>>>(adj, counts, elist,
                                       X, W, att_src, att_dst,
                                       ft16, asrc, adst, Spart);
  colsum_par_kernel<<<128, 256, 0, stream>>>(Spart, S);
  gather_all_kernel<<<N_NODES / 8, 512, 0, stream>>>(counts, elist, ft16,
                                                     asrc, adst, S, out);
}